// Round 7
// baseline (153.498 us; speedup 1.0000x reference)
//
#include <hip/hip_runtime.h>

// Problem: B=8, CTX=1024, D=512 RoPE attention head, fp32 in/out, bf16-tolerance.
#define BATCH 8
#define CTXN  1024
#define DMODEL 512

using short8  = __attribute__((ext_vector_type(8))) short;
using f32x16  = __attribute__((ext_vector_type(16))) float;

typedef const void __attribute__((address_space(1)))* as1_cvp;
typedef void __attribute__((address_space(3)))* as3_vp;

__device__ __forceinline__ unsigned short f2bf(float f) {
  unsigned int u = __float_as_uint(f);
  u += 0x7fffu + ((u >> 16) & 1u);   // round-to-nearest-even
  return (unsigned short)(u >> 16);
}

// ---------------- fused prep: bf16 casts + RoPE cos/sin table, one launch ----------------
#define X4  1048576   // 8*1024*512/4
#define W4  65536     // 512*512/4
#define CAST_BLOCKS 4864   // (X4+3*W4)/256
__global__ __launch_bounds__(256) void prep_all(const float* __restrict__ x,
                                                const float* __restrict__ wq,
                                                const float* __restrict__ wk,
                                                const float* __restrict__ wv,
                                                unsigned short* __restrict__ xb,
                                                unsigned short* __restrict__ wb,
                                                float2* __restrict__ tab) {
  if (blockIdx.x < CAST_BLOCKS) {
    int gid = blockIdx.x * 256 + threadIdx.x;
    const float4* src; ushort4* dst;
    if (gid < X4)                { src = (const float4*)x  + gid;              dst = (ushort4*)xb + gid; }
    else if (gid < X4 + W4)      { int o = gid - X4;        src = (const float4*)wq + o; dst = (ushort4*)wb + o; }
    else if (gid < X4 + 2 * W4)  { int o = gid - X4 - W4;   src = (const float4*)wk + o; dst = (ushort4*)(wb + 262144) + o; }
    else                         { int o = gid - X4 - 2*W4; src = (const float4*)wv + o; dst = (ushort4*)(wb + 524288) + o; }
    float4 f = *src;
    ushort4 u;
    u.x = f2bf(f.x); u.y = f2bf(f.y); u.z = f2bf(f.z); u.w = f2bf(f.w);
    *dst = u;
  } else {
    int c = blockIdx.x - CAST_BLOCKS;   // 0..1023
    int i = threadIdx.x;                // 0..255 = D/2
    float freq = exp2f((float)i * (-13.287712379549449f / 256.0f));  // 10000^(-i/256)
    float th = (float)c * freq;
    float sn, cs;
    sincosf(th, &sn, &cs);
    tab[c * 256 + i] = make_float2(cs, sn);
  }
}

// ---------------- GEMM core for QKV (unchanged from R6, proven) ----------------
__device__ __forceinline__ void issue_tile(const unsigned short* __restrict__ gA, int ldA,
                                           const unsigned short* __restrict__ gB, int ldB,
                                           unsigned short* sA, unsigned short* sB,
                                           int slot, int tid) {
  unsigned short* dA = sA + (slot << 13);
  unsigned short* dB = sB + (slot << 13);
#pragma unroll
  for (int c = 0; c < 2; ++c) {
    int li  = (c << 9) + tid;
    int row = li >> 3;
    int ch  = (li & 7) ^ (row & 7);
    __builtin_amdgcn_global_load_lds((as1_cvp)(gA + (size_t)row * ldA + (ch << 3)),
                                     (as3_vp)(dA + (li << 3)), 16, 0, 0);
  }
#pragma unroll
  for (int c = 0; c < 2; ++c) {
    int li  = (c << 9) + tid;
    int row = li >> 3;
    int ch  = (li & 7) ^ (row & 7);
    __builtin_amdgcn_global_load_lds((as1_cvp)(gB + (size_t)row * ldB + (ch << 3)),
                                     (as3_vp)(dB + (li << 3)), 16, 0, 0);
  }
}

__device__ __forceinline__ void gemm_pipe(const unsigned short* __restrict__ gA, int ldA,
                                          const unsigned short* __restrict__ gB, int ldB,
                                          int nt, unsigned short* sA, unsigned short* sB,
                                          int tid, f32x16 acc[2]) {
  const int l = tid & 63, w = tid >> 6, wr = w >> 2, wc = w & 3;
  const int cl = l & 31, hi = l >> 5;
  int aoff[2][4], boff[4];
#pragma unroll
  for (int m = 0; m < 2; ++m) {
    int ra = wr * 64 + m * 32 + cl;
#pragma unroll
    for (int ks = 0; ks < 4; ++ks) {
      int kc = ks * 2 + hi;
      aoff[m][ks] = ra * 64 + ((kc ^ (ra & 7)) << 3);
    }
  }
  {
    int rb = wc * 32 + cl;
#pragma unroll
    for (int ks = 0; ks < 4; ++ks) {
      int kc = ks * 2 + hi;
      boff[ks] = rb * 64 + ((kc ^ (rb & 7)) << 3);
    }
  }
  issue_tile(gA, ldA, gB, ldB, sA, sB, 0, tid);
  issue_tile(gA + 64, ldA, gB + 64, ldB, sA, sB, 1, tid);
  asm volatile("s_waitcnt vmcnt(4)" ::: "memory");
  __builtin_amdgcn_s_barrier();
  __builtin_amdgcn_sched_barrier(0);

  for (int t = 0; t < nt; ++t) {
    const unsigned short* sAb = sA + ((t & 1) << 13);
    const unsigned short* sBb = sB + ((t & 1) << 13);
    short8 af[2][4], bfv[4];
    af[0][0] = *(const short8*)(sAb + aoff[0][0]);
    af[1][0] = *(const short8*)(sAb + aoff[1][0]);
    bfv[0]   = *(const short8*)(sBb + boff[0]);
#pragma unroll
    for (int ks = 0; ks < 3; ++ks) {
      af[0][ks + 1] = *(const short8*)(sAb + aoff[0][ks + 1]);
      af[1][ks + 1] = *(const short8*)(sAb + aoff[1][ks + 1]);
      bfv[ks + 1]   = *(const short8*)(sBb + boff[ks + 1]);
      asm volatile("s_waitcnt lgkmcnt(3)" ::: "memory");
      __builtin_amdgcn_sched_barrier(0);
      __builtin_amdgcn_s_setprio(1);
      acc[0] = __builtin_amdgcn_mfma_f32_32x32x16_bf16(af[0][ks], bfv[ks], acc[0], 0, 0, 0);
      acc[1] = __builtin_amdgcn_mfma_f32_32x32x16_bf16(af[1][ks], bfv[ks], acc[1], 0, 0, 0);
      __builtin_amdgcn_s_setprio(0);
    }
    asm volatile("s_waitcnt lgkmcnt(0)" ::: "memory");
    __builtin_amdgcn_sched_barrier(0);
    __builtin_amdgcn_s_barrier();
    if (t + 2 < nt) {
      issue_tile(gA + (size_t)(t + 2) * 64, ldA, gB + (size_t)(t + 2) * 64, ldB, sA, sB, t & 1, tid);
      asm volatile("s_waitcnt vmcnt(4)" ::: "memory");
    } else {
      asm volatile("s_waitcnt vmcnt(0)" ::: "memory");
    }
    __builtin_amdgcn_sched_barrier(0);
    __builtin_amdgcn_s_setprio(1);
    acc[0] = __builtin_amdgcn_mfma_f32_32x32x16_bf16(af[0][3], bfv[3], acc[0], 0, 0, 0);
    acc[1] = __builtin_amdgcn_mfma_f32_32x32x16_bf16(af[1][3], bfv[3], acc[1], 0, 0, 0);
    __builtin_amdgcn_s_setprio(0);
    __builtin_amdgcn_s_barrier();
    __builtin_amdgcn_sched_barrier(0);
  }
}

// C/D mapping (m74/m101): col = lane&31, row = (reg&3) + 8*(reg>>2) + 4*(lane>>5).

// ---------------- K2: QKV projection + bias + RoPE, V transposed (unchanged) ----------------
__global__ __launch_bounds__(512, 4) void qkv_kernel(const unsigned short* __restrict__ xb,
                                                     const unsigned short* __restrict__ wb,
                                                     const float* __restrict__ bq,
                                                     const float* __restrict__ bk,
                                                     const float* __restrict__ bv,
                                                     const float2* __restrict__ tab,
                                                     unsigned short* __restrict__ qrot,
                                                     unsigned short* __restrict__ krot,
                                                     unsigned short* __restrict__ vt) {
  __shared__ __align__(16) unsigned short sA[2 * 8192];
  __shared__ __align__(16) unsigned short sB[2 * 8192];
  int t = threadIdx.x, w = t >> 6, l = t & 63, wr = w >> 2, wc = w & 3;
  int cl = l & 31, hi = l >> 5;
  int m0 = blockIdx.x * 128, n0 = blockIdx.y * 128;
  f32x16 acc[2] = {};
  gemm_pipe(xb + (size_t)m0 * 512, 512, wb + (size_t)n0 * 512, 512, 8, sA, sB, t, acc);

  int sec = n0 >> 9;
  const float* bias = (sec == 0) ? bq : (sec == 1) ? bk : bv;
  unsigned short* qk_dst = (sec == 0) ? qrot : krot;
  int e = (n0 + wc * 32 + cl) & 511;
  float bsv = bias[e];
  if (sec < 2) {
    int i2 = e >> 1;
#pragma unroll
    for (int m = 0; m < 2; ++m) {
      int rowb = m0 + wr * 64 + m * 32 + 4 * hi;
#pragma unroll
      for (int r = 0; r < 16; ++r) {
        int mg = rowb + (r & 3) + 8 * (r >> 2);
        int cpos = mg & (CTXN - 1);
        float val  = acc[m][r] + bsv;
        float part = __shfl_xor(val, 1);
        float2 cs  = tab[cpos * 256 + i2];
        float o = (e & 1) ? fmaf(part, cs.y, val * cs.x)
                          : fmaf(-part, cs.y, val * cs.x);
        qk_dst[(size_t)mg * 512 + e] = f2bf(o);
      }
    }
  } else {
#pragma unroll
    for (int m = 0; m < 2; ++m) {
      int rowb0 = m0 + wr * 64 + m * 32 + 4 * hi;
#pragma unroll
      for (int q = 0; q < 4; ++q) {
        int rowb = rowb0 + 8 * q;
        int bidx = rowb >> 10;
        int cpos = rowb & (CTXN - 1);
        ushort4 pk;
        pk.x = f2bf(acc[m][q * 4 + 0] + bsv);
        pk.y = f2bf(acc[m][q * 4 + 1] + bsv);
        pk.z = f2bf(acc[m][q * 4 + 2] + bsv);
        pk.w = f2bf(acc[m][q * 4 + 3] + bsv);
        *(ushort4*)(vt + ((size_t)bidx * 512 + e) * 1024 + cpos) = pk;  // vt[b][d][c]
      }
    }
  }
}

// ---------------- K3: fused flash attention (scores+softmax+PV) ----------------
// Block = (strip s of 32 q-rows, batch b), wgid = s*8+b so XCD<->b (3MB L2 set).
// 8 waves: per kv-tile (KVB=256) wave w computes S-quadrant 32x32 (cols w*32) and
// owns O d-slice [w*64, w*64+64). K/V/Q frags direct from L2 (m169: no staging).
#define KVB 256
#define PPITCH 264   // bf16 elems, 16B-aligned rows, breaks power-of-2 bank stride

__global__ __launch_bounds__(512, 2) void fattn_kernel(const unsigned short* __restrict__ qrot,
                                                       const unsigned short* __restrict__ krot,
                                                       const unsigned short* __restrict__ vt,
                                                       float* __restrict__ out) {
  int wgid = blockIdx.x;
  int s = wgid >> 3, b = wgid & 7;
  int iq0 = s * 32;
  int kvmax = iq0 + 32;                    // exclusive causal bound
  int njt = (kvmax + KVB - 1) / KVB;

  const unsigned short* Qb = qrot + ((size_t)b << 19) + (size_t)iq0 * 512;
  const unsigned short* Kb = krot + ((size_t)b << 19);
  const unsigned short* Vb = vt   + ((size_t)b << 19);

  __shared__ __align__(16) unsigned short Ps[32 * PPITCH];  // ~17 KB
  __shared__ float redM[32][8];
  __shared__ float redS[32][8];

  int t = threadIdx.x, w = t >> 6, l = t & 63, cl = l & 31, hi = l >> 5;

  f32x16 O0 = {}, O1 = {};
  float m_run[16], l_run[16];
#pragma unroll
  for (int rr = 0; rr < 16; ++rr) { m_run[rr] = -3.0e38f; l_run[rr] = 0.0f; }

  const float scale = 0.04419417382415922f;  // 1/sqrt(512)

  for (int jt = 0; jt < njt; ++jt) {
    int j0 = jt * KVB + w * 32;
    bool act = (j0 < kvmax);                 // quadrant has >=1 valid col
    // ---- QK^T: S quadrant 32x32, K=512, dual chains ----
    f32x16 aE = {}, aO = {};
    if (act) {
      const unsigned short* Kw = Kb + (size_t)j0 * 512;
#pragma unroll
      for (int ks = 0; ks < 32; ++ks) {
        short8 qa = *(const short8*)(Qb + (size_t)cl * 512 + ks * 16 + hi * 8);
        short8 kf = *(const short8*)(Kw + (size_t)cl * 512 + ks * 16 + hi * 8);
        if (ks & 1) aO = __builtin_amdgcn_mfma_f32_32x32x16_bf16(qa, kf, aO, 0, 0, 0);
        else        aE = __builtin_amdgcn_mfma_f32_32x32x16_bf16(qa, kf, aE, 0, 0, 0);
      }
    }
    // ---- scale + causal mask ----
    int jcol = j0 + cl;
    float sv[16];
#pragma unroll
    for (int rr = 0; rr < 16; ++rr) {
      int rowi = iq0 + (rr & 3) + 8 * (rr >> 2) + 4 * hi;
      float xv = (aE[rr] + aO[rr]) * scale;
      sv[rr] = (act && jcol <= rowi) ? xv : -3.0e38f;
    }
    // ---- per-quadrant row max (reduce over cl; xor<32 stays in half) ----
#pragma unroll
    for (int rr = 0; rr < 16; ++rr) {
      float m = sv[rr];
#pragma unroll
      for (int o = 16; o > 0; o >>= 1) m = fmaxf(m, __shfl_xor(m, o));
      if (cl == 0) redM[(rr & 3) + 8 * (rr >> 2) + 4 * hi][w] = m;
    }
    __syncthreads();
    // ---- combine maxes, compute rescale, exp, partial sums, write P ----
    float sc[16];
#pragma unroll
    for (int rr = 0; rr < 16; ++rr) {
      int row = (rr & 3) + 8 * (rr >> 2) + 4 * hi;
      float4 a = *(const float4*)&redM[row][0];
      float4 bq = *(const float4*)&redM[row][4];
      float tm = fmaxf(fmaxf(fmaxf(a.x, a.y), fmaxf(a.z, a.w)),
                       fmaxf(fmaxf(bq.x, bq.y), fmaxf(bq.z, bq.w)));
      float nm = fmaxf(m_run[rr], tm);
      sc[rr] = __expf(m_run[rr] - nm);
      m_run[rr] = nm;
      float p = __expf(sv[rr] - nm);
      sv[rr] = p;
      float sp = p;
#pragma unroll
      for (int o = 16; o > 0; o >>= 1) sp += __shfl_xor(sp, o);
      if (cl == 0) redS[row][w] = sp;
      Ps[row * PPITCH + w * 32 + cl] = f2bf(p);
      O0[rr] *= sc[rr];
      O1[rr] *= sc[rr];
    }
    __syncthreads();
    // ---- l update + PV ----
#pragma unroll
    for (int rr = 0; rr < 16; ++rr) {
      int row = (rr & 3) + 8 * (rr >> 2) + 4 * hi;
      float4 a = *(const float4*)&redS[row][0];
      float4 bq = *(const float4*)&redS[row][4];
      l_run[rr] = l_run[rr] * sc[rr] + (a.x + a.y + a.z + a.w + bq.x + bq.y + bq.z + bq.w);
    }
    int kkmax = min(16, (kvmax - jt * KVB + 15) >> 4);
    const unsigned short* Vw = Vb + (size_t)(w * 64) * 1024 + jt * KVB;
    for (int kk = 0; kk < kkmax; ++kk) {
      short8 pa = *(const short8*)(Ps + cl * PPITCH + kk * 16 + hi * 8);
      short8 v0 = *(const short8*)(Vw + (size_t)cl * 1024 + kk * 16 + hi * 8);
      short8 v1 = *(const short8*)(Vw + (size_t)(cl + 32) * 1024 + kk * 16 + hi * 8);
      O0 = __builtin_amdgcn_mfma_f32_32x32x16_bf16(pa, v0, O0, 0, 0, 0);
      O1 = __builtin_amdgcn_mfma_f32_32x32x16_bf16(pa, v1, O1, 0, 0, 0);
    }
    __syncthreads();   // Ps/red reuse guard for next tile
  }
  // ---- normalize + store ----
  float* ob = out + ((size_t)b << 19) + (size_t)iq0 * 512;
#pragma unroll
  for (int rr = 0; rr < 16; ++rr) {
    int row = (rr & 3) + 8 * (rr >> 2) + 4 * hi;
    float inv = 1.0f / l_run[rr];
    ob[(size_t)row * 512 + w * 64 + cl]      = O0[rr] * inv;
    ob[(size_t)row * 512 + w * 64 + 32 + cl] = O1[rr] * inv;
  }
}

// ---------------- launch ----------------
extern "C" void kernel_launch(void* const* d_in, const int* in_sizes, int n_in,
                              void* d_out, int out_size, void* d_ws, size_t ws_size,
                              hipStream_t stream) {
  const float* x  = (const float*)d_in[0];
  const float* wq = (const float*)d_in[1];
  const float* bq = (const float*)d_in[2];
  const float* wk = (const float*)d_in[3];
  const float* bk = (const float*)d_in[4];
  const float* wv = (const float*)d_in[5];
  const float* bv = (const float*)d_in[6];
  float* out = (float*)d_out;

  char* ws = (char*)d_ws;
  float2*         tab  = (float2*)(ws);                          //  2 MB
  unsigned short* xb   = (unsigned short*)(ws + (2ull  << 20));  //  8 MB
  unsigned short* wb   = (unsigned short*)(ws + (10ull << 20));  //  1.5 MB
  unsigned short* qrot = (unsigned short*)(ws + (12ull << 20));  //  8 MB
  unsigned short* krot = (unsigned short*)(ws + (20ull << 20));  //  8 MB
  unsigned short* vt   = (unsigned short*)(ws + (28ull << 20));  //  8 MB -> total 36 MB

  prep_all<<<dim3(CAST_BLOCKS + CTXN), dim3(256), 0, stream>>>(x, wq, wk, wv, xb, wb, tab);
  qkv_kernel<<<dim3(64, 12), dim3(512), 0, stream>>>(xb, wb, bq, bk, bv, tab, qrot, krot, vt);
  fattn_kernel<<<dim3(256), dim3(512), 0, stream>>>(qrot, krot, vt, out);
}

// Round 9
// 122.131 us; speedup vs baseline: 1.2568x; 1.2568x over previous
//
#include <hip/hip_runtime.h>

// Problem: B=8, CTX=1024, D=512 RoPE attention head, fp32 in/out, bf16-tolerance.
#define BATCH 8
#define CTXN  1024
#define DMODEL 512

using short8  = __attribute__((ext_vector_type(8))) short;
using f32x4   = __attribute__((ext_vector_type(4))) float;
using f32x16  = __attribute__((ext_vector_type(16))) float;

typedef const void __attribute__((address_space(1)))* as1_cvp;
typedef void __attribute__((address_space(3)))* as3_vp;

__device__ __forceinline__ unsigned short f2bf(float f) {
  unsigned int u = __float_as_uint(f);
  u += 0x7fffu + ((u >> 16) & 1u);   // round-to-nearest-even
  return (unsigned short)(u >> 16);
}

// ---------------- fused prep: bf16 casts + RoPE cos/sin table, one launch ----------------
#define X4  1048576   // 8*1024*512/4
#define W4  65536     // 512*512/4
#define CAST_BLOCKS 4864   // (X4+3*W4)/256
__global__ __launch_bounds__(256) void prep_all(const float* __restrict__ x,
                                                const float* __restrict__ wq,
                                                const float* __restrict__ wk,
                                                const float* __restrict__ wv,
                                                unsigned short* __restrict__ xb,
                                                unsigned short* __restrict__ wb,
                                                float2* __restrict__ tab) {
  if (blockIdx.x < CAST_BLOCKS) {
    int gid = blockIdx.x * 256 + threadIdx.x;
    const float4* src; ushort4* dst;
    if (gid < X4)                { src = (const float4*)x  + gid;              dst = (ushort4*)xb + gid; }
    else if (gid < X4 + W4)      { int o = gid - X4;        src = (const float4*)wq + o; dst = (ushort4*)wb + o; }
    else if (gid < X4 + 2 * W4)  { int o = gid - X4 - W4;   src = (const float4*)wk + o; dst = (ushort4*)(wb + 262144) + o; }
    else                         { int o = gid - X4 - 2*W4; src = (const float4*)wv + o; dst = (ushort4*)(wb + 524288) + o; }
    float4 f = *src;
    ushort4 u;
    u.x = f2bf(f.x); u.y = f2bf(f.y); u.z = f2bf(f.z); u.w = f2bf(f.w);
    *dst = u;
  } else {
    int c = blockIdx.x - CAST_BLOCKS;   // 0..1023
    int i = threadIdx.x;                // 0..255 = D/2
    float freq = exp2f((float)i * (-13.287712379549449f / 256.0f));  // 10000^(-i/256)
    float th = (float)c * freq;
    float sn, cs;
    sincosf(th, &sn, &cs);
    tab[c * 256 + i] = make_float2(cs, sn);
  }
}

// ---------------- GEMM core for QKV (unchanged from R6, proven) ----------------
__device__ __forceinline__ void issue_tile(const unsigned short* __restrict__ gA, int ldA,
                                           const unsigned short* __restrict__ gB, int ldB,
                                           unsigned short* sA, unsigned short* sB,
                                           int slot, int tid) {
  unsigned short* dA = sA + (slot << 13);
  unsigned short* dB = sB + (slot << 13);
#pragma unroll
  for (int c = 0; c < 2; ++c) {
    int li  = (c << 9) + tid;
    int row = li >> 3;
    int ch  = (li & 7) ^ (row & 7);
    __builtin_amdgcn_global_load_lds((as1_cvp)(gA + (size_t)row * ldA + (ch << 3)),
                                     (as3_vp)(dA + (li << 3)), 16, 0, 0);
  }
#pragma unroll
  for (int c = 0; c < 2; ++c) {
    int li  = (c << 9) + tid;
    int row = li >> 3;
    int ch  = (li & 7) ^ (row & 7);
    __builtin_amdgcn_global_load_lds((as1_cvp)(gB + (size_t)row * ldB + (ch << 3)),
                                     (as3_vp)(dB + (li << 3)), 16, 0, 0);
  }
}

__device__ __forceinline__ void gemm_pipe(const unsigned short* __restrict__ gA, int ldA,
                                          const unsigned short* __restrict__ gB, int ldB,
                                          int nt, unsigned short* sA, unsigned short* sB,
                                          int tid, f32x16 acc[2]) {
  const int l = tid & 63, w = tid >> 6, wr = w >> 2, wc = w & 3;
  const int cl = l & 31, hi = l >> 5;
  int aoff[2][4], boff[4];
#pragma unroll
  for (int m = 0; m < 2; ++m) {
    int ra = wr * 64 + m * 32 + cl;
#pragma unroll
    for (int ks = 0; ks < 4; ++ks) {
      int kc = ks * 2 + hi;
      aoff[m][ks] = ra * 64 + ((kc ^ (ra & 7)) << 3);
    }
  }
  {
    int rb = wc * 32 + cl;
#pragma unroll
    for (int ks = 0; ks < 4; ++ks) {
      int kc = ks * 2 + hi;
      boff[ks] = rb * 64 + ((kc ^ (rb & 7)) << 3);
    }
  }
  issue_tile(gA, ldA, gB, ldB, sA, sB, 0, tid);
  issue_tile(gA + 64, ldA, gB + 64, ldB, sA, sB, 1, tid);
  asm volatile("s_waitcnt vmcnt(4)" ::: "memory");
  __builtin_amdgcn_s_barrier();
  __builtin_amdgcn_sched_barrier(0);

  for (int t = 0; t < nt; ++t) {
    const unsigned short* sAb = sA + ((t & 1) << 13);
    const unsigned short* sBb = sB + ((t & 1) << 13);
    short8 af[2][4], bfv[4];
    af[0][0] = *(const short8*)(sAb + aoff[0][0]);
    af[1][0] = *(const short8*)(sAb + aoff[1][0]);
    bfv[0]   = *(const short8*)(sBb + boff[0]);
#pragma unroll
    for (int ks = 0; ks < 3; ++ks) {
      af[0][ks + 1] = *(const short8*)(sAb + aoff[0][ks + 1]);
      af[1][ks + 1] = *(const short8*)(sAb + aoff[1][ks + 1]);
      bfv[ks + 1]   = *(const short8*)(sBb + boff[ks + 1]);
      asm volatile("s_waitcnt lgkmcnt(3)" ::: "memory");
      __builtin_amdgcn_sched_barrier(0);
      __builtin_amdgcn_s_setprio(1);
      acc[0] = __builtin_amdgcn_mfma_f32_32x32x16_bf16(af[0][ks], bfv[ks], acc[0], 0, 0, 0);
      acc[1] = __builtin_amdgcn_mfma_f32_32x32x16_bf16(af[1][ks], bfv[ks], acc[1], 0, 0, 0);
      __builtin_amdgcn_s_setprio(0);
    }
    asm volatile("s_waitcnt lgkmcnt(0)" ::: "memory");
    __builtin_amdgcn_sched_barrier(0);
    __builtin_amdgcn_s_barrier();
    if (t + 2 < nt) {
      issue_tile(gA + (size_t)(t + 2) * 64, ldA, gB + (size_t)(t + 2) * 64, ldB, sA, sB, t & 1, tid);
      asm volatile("s_waitcnt vmcnt(4)" ::: "memory");
    } else {
      asm volatile("s_waitcnt vmcnt(0)" ::: "memory");
    }
    __builtin_amdgcn_sched_barrier(0);
    __builtin_amdgcn_s_setprio(1);
    acc[0] = __builtin_amdgcn_mfma_f32_32x32x16_bf16(af[0][3], bfv[3], acc[0], 0, 0, 0);
    acc[1] = __builtin_amdgcn_mfma_f32_32x32x16_bf16(af[1][3], bfv[3], acc[1], 0, 0, 0);
    __builtin_amdgcn_s_setprio(0);
    __builtin_amdgcn_s_barrier();
    __builtin_amdgcn_sched_barrier(0);
  }
}

// C/D mapping 32x32 (m74/m101): col = lane&31, row = (reg&3) + 8*(reg>>2) + 4*(lane>>5).

// ---------------- K2: QKV projection + bias + RoPE, V transposed (unchanged) ----------------
__global__ __launch_bounds__(512, 4) void qkv_kernel(const unsigned short* __restrict__ xb,
                                                     const unsigned short* __restrict__ wb,
                                                     const float* __restrict__ bq,
                                                     const float* __restrict__ bk,
                                                     const float* __restrict__ bv,
                                                     const float2* __restrict__ tab,
                                                     unsigned short* __restrict__ qrot,
                                                     unsigned short* __restrict__ krot,
                                                     unsigned short* __restrict__ vt) {
  __shared__ __align__(16) unsigned short sA[2 * 8192];
  __shared__ __align__(16) unsigned short sB[2 * 8192];
  int t = threadIdx.x, w = t >> 6, l = t & 63, wr = w >> 2, wc = w & 3;
  int cl = l & 31, hi = l >> 5;
  int m0 = blockIdx.x * 128, n0 = blockIdx.y * 128;
  f32x16 acc[2] = {};
  gemm_pipe(xb + (size_t)m0 * 512, 512, wb + (size_t)n0 * 512, 512, 8, sA, sB, t, acc);

  int sec = n0 >> 9;
  const float* bias = (sec == 0) ? bq : (sec == 1) ? bk : bv;
  unsigned short* qk_dst = (sec == 0) ? qrot : krot;
  int e = (n0 + wc * 32 + cl) & 511;
  float bsv = bias[e];
  if (sec < 2) {
    int i2 = e >> 1;
#pragma unroll
    for (int m = 0; m < 2; ++m) {
      int rowb = m0 + wr * 64 + m * 32 + 4 * hi;
#pragma unroll
      for (int r = 0; r < 16; ++r) {
        int mg = rowb + (r & 3) + 8 * (r >> 2);
        int cpos = mg & (CTXN - 1);
        float val  = acc[m][r] + bsv;
        float part = __shfl_xor(val, 1);
        float2 cs  = tab[cpos * 256 + i2];
        float o = (e & 1) ? fmaf(part, cs.y, val * cs.x)
                          : fmaf(-part, cs.y, val * cs.x);
        qk_dst[(size_t)mg * 512 + e] = f2bf(o);
      }
    }
  } else {
#pragma unroll
    for (int m = 0; m < 2; ++m) {
      int rowb0 = m0 + wr * 64 + m * 32 + 4 * hi;
#pragma unroll
      for (int q = 0; q < 4; ++q) {
        int rowb = rowb0 + 8 * q;
        int bidx = rowb >> 10;
        int cpos = rowb & (CTXN - 1);
        ushort4 pk;
        pk.x = f2bf(acc[m][q * 4 + 0] + bsv);
        pk.y = f2bf(acc[m][q * 4 + 1] + bsv);
        pk.z = f2bf(acc[m][q * 4 + 2] + bsv);
        pk.w = f2bf(acc[m][q * 4 + 3] + bsv);
        *(ushort4*)(vt + ((size_t)bidx * 512 + e) * 1024 + cpos) = pk;  // vt[b][d][c]
      }
    }
  }
}

// ---------------- K3: fused flash attention v2 (swapped QK^T, lane-local softmax) --------
// 512 blocks x 256 thr (2/CU). Block -> (strip of 16 q-rows, batch). CU-paired blocks
// (id, id+256) get complementary strips s and 63-s -> uniform per-CU work.
// 4 waves: QK^T wave w owns kv-quad [jb+16w, +16); PV wave w owns d-slice [128w, +128).
// 16x16x32 layouts: A: row=l&15,k=(l>>4)*8+j ; B: col=l&15,k=(l>>4)*8+j ;
// C/D: col=l&15, row=(l>>4)*4+r.  Swapped mfma(K,Q): C col = q-row (lane-local softmax).
#define QB 16
#define KVB 64

__global__ __launch_bounds__(256, 2) void fattn2(const unsigned short* __restrict__ qrot,
                                                 const unsigned short* __restrict__ krot,
                                                 const unsigned short* __restrict__ vt,
                                                 float* __restrict__ out) {
  int b = blockIdx.x & 7;
  int u = blockIdx.x >> 3;            // 0..63
  int s = (u < 32) ? u : 95 - u;      // complementary pairing across +256
  int iq0 = s * QB;
  int kvmax = iq0 + QB;               // causal bound (exclusive)
  int njt = (kvmax + KVB - 1) / KVB;

  const unsigned short* Qb = qrot + ((size_t)b << 19);
  const unsigned short* Kb = krot + ((size_t)b << 19);
  const unsigned short* Vb = vt   + ((size_t)b << 19);

  __shared__ __align__(16) unsigned short Qs[QB * 512];   // 16 KB, swizzled
  __shared__ __align__(16) unsigned short Ps[QB * KVB];   // 2 KB, swizzled
  __shared__ float redM[2][QB][4];
  __shared__ float redS[2][QB][4];
  __shared__ float mS[QB], lS[QB], scS[QB];

  int t = threadIdx.x, w = t >> 6, l = t & 63;
  int q4 = l & 15, hi4 = l >> 4;      // hi4 in 0..3

  // stage Q strip (pre-swizzled global source, linear LDS dest)
#pragma unroll
  for (int c = 0; c < 4; ++c) {
    int li = (c << 8) + t;            // 0..1023 16B chunks
    int row = li >> 6, ch = li & 63;
    int chs = (ch & 56) | ((ch ^ row) & 7);
    __builtin_amdgcn_global_load_lds((as1_cvp)(Qb + (size_t)(iq0 + row) * 512 + (chs << 3)),
                                     (as3_vp)(Qs + (li << 3)), 16, 0, 0);
  }
  if (t < QB) { mS[t] = -3.0e38f; lS[t] = 0.0f; }
  asm volatile("s_waitcnt vmcnt(0)" ::: "memory");
  __syncthreads();

  f32x4 O[8] = {};                    // O[16q][128d]: n-frags of 16 d
  const float scale = 0.04419417382415922f;  // 1/sqrt(512)

  for (int jt = 0; jt < njt; ++jt) {
    int jb = jt * KVB;
    int par = jt & 1;
    int kq0 = jb + w * 16;            // this wave's kv quadrant
    float m_old = mS[q4];             // safe: writer is after sync1 of this jt
    // ---- (a) swapped QK^T: quad 16kv x 16q, K=512, dual acc chains ----
    f32x4 a0 = {}, a1 = {};
    bool act = (kq0 <= iq0 + QB - 1);
    if (act) {
      const unsigned short* Kw = Kb + (size_t)(kq0 + q4) * 512 + hi4 * 8;
#pragma unroll
      for (int ks = 0; ks < 16; ++ks) {
        short8 kf = *(const short8*)(Kw + ks * 32);
        int ch = ks * 4 + hi4;
        int chs = (ch & 56) | ((ch ^ q4) & 7);
        short8 qf = *(const short8*)(Qs + q4 * 512 + (chs << 3));
        if (ks & 1) a1 = __builtin_amdgcn_mfma_f32_16x16x32_bf16(kf, qf, a1, 0, 0, 0);
        else        a0 = __builtin_amdgcn_mfma_f32_16x16x32_bf16(kf, qf, a0, 0, 0, 0);
      }
    }
    // lane holds: q-row = q4, kv = kq0 + hi4*4 + r
    float sv[4];
    int qrow = iq0 + q4;
#pragma unroll
    for (int r = 0; r < 4; ++r) {
      float xv = (a0[r] + a1[r]) * scale;
      int kv = kq0 + hi4 * 4 + r;
      sv[r] = (act && kv <= qrow) ? xv : -3.0e38f;
    }
    float m4 = fmaxf(fmaxf(sv[0], sv[1]), fmaxf(sv[2], sv[3]));
    m4 = fmaxf(m4, __shfl_xor(m4, 16));
    m4 = fmaxf(m4, __shfl_xor(m4, 32));
    if (l < 16) redM[par][l][w] = m4;
    __syncthreads();                                   // sync1
    // ---- (b) combine max, exp, partial sums, pack P ----
    float4 rm = *(const float4*)&redM[par][q4][0];
    float m_tile = fmaxf(fmaxf(rm.x, rm.y), fmaxf(rm.z, rm.w));
    float m_new = fmaxf(m_old, m_tile);
    float sc = __expf(m_old - m_new);
    float p0 = __expf(sv[0] - m_new);
    float p1 = __expf(sv[1] - m_new);
    float p2 = __expf(sv[2] - m_new);
    float p3 = __expf(sv[3] - m_new);
    float psum = (p0 + p1) + (p2 + p3);
    psum += __shfl_xor(psum, 16);
    psum += __shfl_xor(psum, 32);
    if (l < 16) redS[par][l][w] = psum;
    {
      unsigned int u0 = (unsigned int)f2bf(p0) | ((unsigned int)f2bf(p1) << 16);
      unsigned int u1 = (unsigned int)f2bf(p2) | ((unsigned int)f2bf(p3) << 16);
      int ch = (w * 16 + hi4 * 4) >> 3;                // w*2 + (hi4>>1)
      int chs = ch ^ (q4 & 7);
      *(uint2*)((char*)Ps + q4 * 128 + chs * 16 + (hi4 & 1) * 8) = make_uint2(u0, u1);
    }
    if (w == 0 && l < 16) { mS[l] = m_new; scS[l] = sc; }
    __syncthreads();                                   // sync2
    // ---- (c) l update (wave0), O rescale, PV ----
    if (w == 0 && l < 16) {
      float4 rs = *(const float4*)&redS[par][l][0];
      lS[l] = lS[l] * scS[l] + (rs.x + rs.y + rs.z + rs.w);
    }
    float s0 = scS[hi4 * 4 + 0], s1 = scS[hi4 * 4 + 1],
          s2 = scS[hi4 * 4 + 2], s3 = scS[hi4 * 4 + 3];
#pragma unroll
    for (int n = 0; n < 8; ++n) {
      O[n][0] *= s0; O[n][1] *= s1; O[n][2] *= s2; O[n][3] *= s3;
    }
    int ksmax = min(2, (kvmax - jb + 31) >> 5);        // FIX: cap at KVB/32=2 sub-tiles
    for (int kq = 0; kq < ksmax; ++kq) {
      int ch = kq * 4 + hi4;
      int chs = ch ^ (q4 & 7);
      short8 pa = *(const short8*)((const char*)Ps + q4 * 128 + chs * 16);
      const unsigned short* Vw = Vb + (size_t)(w * 128 + q4) * 1024 + jb + kq * 32 + hi4 * 8;
#pragma unroll
      for (int n = 0; n < 8; ++n) {
        short8 vb = *(const short8*)(Vw + (size_t)(n * 16) * 1024);
        O[n] = __builtin_amdgcn_mfma_f32_16x16x32_bf16(pa, vb, O[n], 0, 0, 0);
      }
    }
  }
  __syncthreads();
  // epilogue: normalize + store
  float* ob = out + ((size_t)b << 19) + (size_t)iq0 * 512;
  float i0 = 1.0f / lS[hi4 * 4 + 0], i1 = 1.0f / lS[hi4 * 4 + 1],
        i2 = 1.0f / lS[hi4 * 4 + 2], i3 = 1.0f / lS[hi4 * 4 + 3];
#pragma unroll
  for (int n = 0; n < 8; ++n) {
    int d = w * 128 + n * 16 + q4;
    ob[(size_t)(hi4 * 4 + 0) * 512 + d] = O[n][0] * i0;
    ob[(size_t)(hi4 * 4 + 1) * 512 + d] = O[n][1] * i1;
    ob[(size_t)(hi4 * 4 + 2) * 512 + d] = O[n][2] * i2;
    ob[(size_t)(hi4 * 4 + 3) * 512 + d] = O[n][3] * i3;
  }
}

// ---------------- launch ----------------
extern "C" void kernel_launch(void* const* d_in, const int* in_sizes, int n_in,
                              void* d_out, int out_size, void* d_ws, size_t ws_size,
                              hipStream_t stream) {
  const float* x  = (const float*)d_in[0];
  const float* wq = (const float*)d_in[1];
  const float* bq = (const float*)d_in[2];
  const float* wk = (const float*)d_in[3];
  const float* bk = (const float*)d_in[4];
  const float* wv = (const float*)d_in[5];
  const float* bv = (const float*)d_in[6];
  float* out = (float*)d_out;

  char* ws = (char*)d_ws;
  float2*         tab  = (float2*)(ws);                          //  2 MB
  unsigned short* xb   = (unsigned short*)(ws + (2ull  << 20));  //  8 MB
  unsigned short* wb   = (unsigned short*)(ws + (10ull << 20));  //  1.5 MB
  unsigned short* qrot = (unsigned short*)(ws + (12ull << 20));  //  8 MB
  unsigned short* krot = (unsigned short*)(ws + (20ull << 20));  //  8 MB
  unsigned short* vt   = (unsigned short*)(ws + (28ull << 20));  //  8 MB -> total 36 MB

  prep_all<<<dim3(CAST_BLOCKS + CTXN), dim3(256), 0, stream>>>(x, wq, wk, wv, xb, wb, tab);
  qkv_kernel<<<dim3(64, 12), dim3(512), 0, stream>>>(xb, wb, bq, bk, bv, tab, qrot, krot, vt);
  fattn2<<<dim3(512), dim3(256), 0, stream>>>(qrot, krot, vt, out);
}

// Round 10
// 73.877 us; speedup vs baseline: 2.0778x; 1.6532x over previous
//
#include <hip/hip_runtime.h>

// Problem: B=8, CTX=1024, D=512 RoPE attention head, fp32 in/out, bf16-tolerance.
#define BATCH 8
#define CTXN  1024
#define DMODEL 512

using short8  = __attribute__((ext_vector_type(8))) short;
using f32x16  = __attribute__((ext_vector_type(16))) float;

typedef const void __attribute__((address_space(1)))* as1_cvp;
typedef void __attribute__((address_space(3)))* as3_vp;

__device__ __forceinline__ unsigned short f2bf(float f) {
  unsigned int u = __float_as_uint(f);
  u += 0x7fffu + ((u >> 16) & 1u);   // round-to-nearest-even
  return (unsigned short)(u >> 16);
}
__device__ __forceinline__ float bf2f(unsigned short u) {
  return __uint_as_float((unsigned int)u << 16);
}

// ---------------- fused prep: bf16 casts + RoPE cos/sin table, one launch ----------------
#define X4  1048576   // 8*1024*512/4
#define W4  65536     // 512*512/4
#define CAST_BLOCKS 4864   // (X4+3*W4)/256
__global__ __launch_bounds__(256) void prep_all(const float* __restrict__ x,
                                                const float* __restrict__ wq,
                                                const float* __restrict__ wk,
                                                const float* __restrict__ wv,
                                                unsigned short* __restrict__ xb,
                                                unsigned short* __restrict__ wb,
                                                float2* __restrict__ tab) {
  if (blockIdx.x < CAST_BLOCKS) {
    int gid = blockIdx.x * 256 + threadIdx.x;
    const float4* src; ushort4* dst;
    if (gid < X4)                { src = (const float4*)x  + gid;              dst = (ushort4*)xb + gid; }
    else if (gid < X4 + W4)      { int o = gid - X4;        src = (const float4*)wq + o; dst = (ushort4*)wb + o; }
    else if (gid < X4 + 2 * W4)  { int o = gid - X4 - W4;   src = (const float4*)wk + o; dst = (ushort4*)(wb + 262144) + o; }
    else                         { int o = gid - X4 - 2*W4; src = (const float4*)wv + o; dst = (ushort4*)(wb + 524288) + o; }
    float4 f = *src;
    ushort4 u;
    u.x = f2bf(f.x); u.y = f2bf(f.y); u.z = f2bf(f.z); u.w = f2bf(f.w);
    *dst = u;
  } else {
    int c = blockIdx.x - CAST_BLOCKS;   // 0..1023
    int i = threadIdx.x;                // 0..255 = D/2
    float freq = exp2f((float)i * (-13.287712379549449f / 256.0f));  // 10000^(-i/256)
    float th = (float)c * freq;
    float sn, cs;
    sincosf(th, &sn, &cs);
    tab[c * 256 + i] = make_float2(cs, sn);
  }
}

// ---------------- GEMM core 128x128 (8 waves) for QKV — R6 proven ----------------
__device__ __forceinline__ void issue_tile(const unsigned short* __restrict__ gA, int ldA,
                                           const unsigned short* __restrict__ gB, int ldB,
                                           unsigned short* sA, unsigned short* sB,
                                           int slot, int tid) {
  unsigned short* dA = sA + (slot << 13);
  unsigned short* dB = sB + (slot << 13);
#pragma unroll
  for (int c = 0; c < 2; ++c) {
    int li  = (c << 9) + tid;
    int row = li >> 3;
    int ch  = (li & 7) ^ (row & 7);
    __builtin_amdgcn_global_load_lds((as1_cvp)(gA + (size_t)row * ldA + (ch << 3)),
                                     (as3_vp)(dA + (li << 3)), 16, 0, 0);
  }
#pragma unroll
  for (int c = 0; c < 2; ++c) {
    int li  = (c << 9) + tid;
    int row = li >> 3;
    int ch  = (li & 7) ^ (row & 7);
    __builtin_amdgcn_global_load_lds((as1_cvp)(gB + (size_t)row * ldB + (ch << 3)),
                                     (as3_vp)(dB + (li << 3)), 16, 0, 0);
  }
}

__device__ __forceinline__ void gemm_pipe(const unsigned short* __restrict__ gA, int ldA,
                                          const unsigned short* __restrict__ gB, int ldB,
                                          int nt, unsigned short* sA, unsigned short* sB,
                                          int tid, f32x16 acc[2]) {
  const int l = tid & 63, w = tid >> 6, wr = w >> 2, wc = w & 3;
  const int cl = l & 31, hi = l >> 5;
  int aoff[2][4], boff[4];
#pragma unroll
  for (int m = 0; m < 2; ++m) {
    int ra = wr * 64 + m * 32 + cl;
#pragma unroll
    for (int ks = 0; ks < 4; ++ks) {
      int kc = ks * 2 + hi;
      aoff[m][ks] = ra * 64 + ((kc ^ (ra & 7)) << 3);
    }
  }
  {
    int rb = wc * 32 + cl;
#pragma unroll
    for (int ks = 0; ks < 4; ++ks) {
      int kc = ks * 2 + hi;
      boff[ks] = rb * 64 + ((kc ^ (rb & 7)) << 3);
    }
  }
  issue_tile(gA, ldA, gB, ldB, sA, sB, 0, tid);
  issue_tile(gA + 64, ldA, gB + 64, ldB, sA, sB, 1, tid);
  asm volatile("s_waitcnt vmcnt(4)" ::: "memory");
  __builtin_amdgcn_s_barrier();
  __builtin_amdgcn_sched_barrier(0);

  for (int t = 0; t < nt; ++t) {
    const unsigned short* sAb = sA + ((t & 1) << 13);
    const unsigned short* sBb = sB + ((t & 1) << 13);
    short8 af[2][4], bfv[4];
    af[0][0] = *(const short8*)(sAb + aoff[0][0]);
    af[1][0] = *(const short8*)(sAb + aoff[1][0]);
    bfv[0]   = *(const short8*)(sBb + boff[0]);
#pragma unroll
    for (int ks = 0; ks < 3; ++ks) {
      af[0][ks + 1] = *(const short8*)(sAb + aoff[0][ks + 1]);
      af[1][ks + 1] = *(const short8*)(sAb + aoff[1][ks + 1]);
      bfv[ks + 1]   = *(const short8*)(sBb + boff[ks + 1]);
      asm volatile("s_waitcnt lgkmcnt(3)" ::: "memory");
      __builtin_amdgcn_sched_barrier(0);
      __builtin_amdgcn_s_setprio(1);
      acc[0] = __builtin_amdgcn_mfma_f32_32x32x16_bf16(af[0][ks], bfv[ks], acc[0], 0, 0, 0);
      acc[1] = __builtin_amdgcn_mfma_f32_32x32x16_bf16(af[1][ks], bfv[ks], acc[1], 0, 0, 0);
      __builtin_amdgcn_s_setprio(0);
    }
    asm volatile("s_waitcnt lgkmcnt(0)" ::: "memory");
    __builtin_amdgcn_sched_barrier(0);
    __builtin_amdgcn_s_barrier();
    if (t + 2 < nt) {
      issue_tile(gA + (size_t)(t + 2) * 64, ldA, gB + (size_t)(t + 2) * 64, ldB, sA, sB, t & 1, tid);
      asm volatile("s_waitcnt vmcnt(4)" ::: "memory");
    } else {
      asm volatile("s_waitcnt vmcnt(0)" ::: "memory");
    }
    __builtin_amdgcn_sched_barrier(0);
    __builtin_amdgcn_s_setprio(1);
    acc[0] = __builtin_amdgcn_mfma_f32_32x32x16_bf16(af[0][3], bfv[3], acc[0], 0, 0, 0);
    acc[1] = __builtin_amdgcn_mfma_f32_32x32x16_bf16(af[1][3], bfv[3], acc[1], 0, 0, 0);
    __builtin_amdgcn_s_setprio(0);
    __builtin_amdgcn_s_barrier();
    __builtin_amdgcn_sched_barrier(0);
  }
}

// ---------------- GEMM core 64x128 (4 waves) for scores/pv — tail-friendly ----------------
// A-tile 64xBK (8KB slot), B-tile 128xBK (16KB slot), BK=64, dbuf -> 48KB LDS, 3 blocks/CU.
__device__ __forceinline__ void issue_tile64(const unsigned short* __restrict__ gA, int ldA,
                                             const unsigned short* __restrict__ gB, int ldB,
                                             unsigned short* sA, unsigned short* sB,
                                             int slot, int tid) {
  unsigned short* dA = sA + (slot << 12);   // 4096 elems = 8KB
  unsigned short* dB = sB + (slot << 13);   // 8192 elems = 16KB
#pragma unroll
  for (int c = 0; c < 2; ++c) {
    int li  = (c << 8) + tid;               // 0..511 (A: 512 chunks)
    int row = li >> 3;
    int ch  = (li & 7) ^ (row & 7);
    __builtin_amdgcn_global_load_lds((as1_cvp)(gA + (size_t)row * ldA + (ch << 3)),
                                     (as3_vp)(dA + (li << 3)), 16, 0, 0);
  }
#pragma unroll
  for (int c = 0; c < 4; ++c) {
    int li  = (c << 8) + tid;               // 0..1023 (B: 1024 chunks)
    int row = li >> 3;
    int ch  = (li & 7) ^ (row & 7);
    __builtin_amdgcn_global_load_lds((as1_cvp)(gB + (size_t)row * ldB + (ch << 3)),
                                     (as3_vp)(dB + (li << 3)), 16, 0, 0);
  }
}

// 4 waves (1x4): per-wave 64 rows x 32 cols = acc[2] of 32x32.
__device__ __forceinline__ void gemm_pipe64(const unsigned short* __restrict__ gA, int ldA,
                                            const unsigned short* __restrict__ gB, int ldB,
                                            int nt, unsigned short* sA, unsigned short* sB,
                                            int tid, f32x16 acc[2]) {
  const int l = tid & 63, w = tid >> 6;
  const int cl = l & 31, hi = l >> 5;
  int aoff[2][4], boff[4];
#pragma unroll
  for (int m = 0; m < 2; ++m) {
    int ra = m * 32 + cl;
#pragma unroll
    for (int ks = 0; ks < 4; ++ks) {
      int kc = ks * 2 + hi;
      aoff[m][ks] = ra * 64 + ((kc ^ (ra & 7)) << 3);
    }
  }
  {
    int rb = w * 32 + cl;
#pragma unroll
    for (int ks = 0; ks < 4; ++ks) {
      int kc = ks * 2 + hi;
      boff[ks] = rb * 64 + ((kc ^ (rb & 7)) << 3);
    }
  }
  issue_tile64(gA, ldA, gB, ldB, sA, sB, 0, tid);
  issue_tile64(gA + 64, ldA, gB + 64, ldB, sA, sB, 1, tid);
  asm volatile("s_waitcnt vmcnt(6)" ::: "memory");   // tile0's 6 done; tile1's 6 in flight
  __builtin_amdgcn_s_barrier();
  __builtin_amdgcn_sched_barrier(0);

  for (int t = 0; t < nt; ++t) {
    const unsigned short* sAb = sA + ((t & 1) << 12);
    const unsigned short* sBb = sB + ((t & 1) << 13);
    short8 af[2][4], bfv[4];
    af[0][0] = *(const short8*)(sAb + aoff[0][0]);
    af[1][0] = *(const short8*)(sAb + aoff[1][0]);
    bfv[0]   = *(const short8*)(sBb + boff[0]);
#pragma unroll
    for (int ks = 0; ks < 3; ++ks) {
      af[0][ks + 1] = *(const short8*)(sAb + aoff[0][ks + 1]);
      af[1][ks + 1] = *(const short8*)(sAb + aoff[1][ks + 1]);
      bfv[ks + 1]   = *(const short8*)(sBb + boff[ks + 1]);
      asm volatile("s_waitcnt lgkmcnt(3)" ::: "memory");
      __builtin_amdgcn_sched_barrier(0);
      __builtin_amdgcn_s_setprio(1);
      acc[0] = __builtin_amdgcn_mfma_f32_32x32x16_bf16(af[0][ks], bfv[ks], acc[0], 0, 0, 0);
      acc[1] = __builtin_amdgcn_mfma_f32_32x32x16_bf16(af[1][ks], bfv[ks], acc[1], 0, 0, 0);
      __builtin_amdgcn_s_setprio(0);
    }
    asm volatile("s_waitcnt lgkmcnt(0)" ::: "memory");
    __builtin_amdgcn_sched_barrier(0);
    __builtin_amdgcn_s_barrier();
    if (t + 2 < nt) {
      issue_tile64(gA + (size_t)(t + 2) * 64, ldA, gB + (size_t)(t + 2) * 64, ldB, sA, sB, t & 1, tid);
      asm volatile("s_waitcnt vmcnt(6)" ::: "memory");
    } else {
      asm volatile("s_waitcnt vmcnt(0)" ::: "memory");
    }
    __builtin_amdgcn_sched_barrier(0);
    __builtin_amdgcn_s_setprio(1);
    acc[0] = __builtin_amdgcn_mfma_f32_32x32x16_bf16(af[0][3], bfv[3], acc[0], 0, 0, 0);
    acc[1] = __builtin_amdgcn_mfma_f32_32x32x16_bf16(af[1][3], bfv[3], acc[1], 0, 0, 0);
    __builtin_amdgcn_s_setprio(0);
    __builtin_amdgcn_s_barrier();
    __builtin_amdgcn_sched_barrier(0);
  }
}

// C/D mapping 32x32 (m74/m101): col = lane&31, row = (reg&3) + 8*(reg>>2) + 4*(lane>>5).

// ---------------- K2: QKV projection + bias + RoPE, V transposed (R6 verbatim) ----------------
__global__ __launch_bounds__(512, 4) void qkv_kernel(const unsigned short* __restrict__ xb,
                                                     const unsigned short* __restrict__ wb,
                                                     const float* __restrict__ bq,
                                                     const float* __restrict__ bk,
                                                     const float* __restrict__ bv,
                                                     const float2* __restrict__ tab,
                                                     unsigned short* __restrict__ qrot,
                                                     unsigned short* __restrict__ krot,
                                                     unsigned short* __restrict__ vt) {
  __shared__ __align__(16) unsigned short sA[2 * 8192];
  __shared__ __align__(16) unsigned short sB[2 * 8192];
  int t = threadIdx.x, w = t >> 6, l = t & 63, wr = w >> 2, wc = w & 3;
  int cl = l & 31, hi = l >> 5;
  int m0 = blockIdx.x * 128, n0 = blockIdx.y * 128;
  f32x16 acc[2] = {};
  gemm_pipe(xb + (size_t)m0 * 512, 512, wb + (size_t)n0 * 512, 512, 8, sA, sB, t, acc);

  int sec = n0 >> 9;
  const float* bias = (sec == 0) ? bq : (sec == 1) ? bk : bv;
  unsigned short* qk_dst = (sec == 0) ? qrot : krot;
  int e = (n0 + wc * 32 + cl) & 511;
  float bsv = bias[e];
  if (sec < 2) {
    int i2 = e >> 1;
#pragma unroll
    for (int m = 0; m < 2; ++m) {
      int rowb = m0 + wr * 64 + m * 32 + 4 * hi;
#pragma unroll
      for (int r = 0; r < 16; ++r) {
        int mg = rowb + (r & 3) + 8 * (r >> 2);
        int cpos = mg & (CTXN - 1);
        float val  = acc[m][r] + bsv;
        float part = __shfl_xor(val, 1);
        float2 cs  = tab[cpos * 256 + i2];
        float o = (e & 1) ? fmaf(part, cs.y, val * cs.x)
                          : fmaf(-part, cs.y, val * cs.x);
        qk_dst[(size_t)mg * 512 + e] = f2bf(o);
      }
    }
  } else {
#pragma unroll
    for (int m = 0; m < 2; ++m) {
      int rowb0 = m0 + wr * 64 + m * 32 + 4 * hi;
#pragma unroll
      for (int q = 0; q < 4; ++q) {
        int rowb = rowb0 + 8 * q;
        int bidx = rowb >> 10;
        int cpos = rowb & (CTXN - 1);
        ushort4 pk;
        pk.x = f2bf(acc[m][q * 4 + 0] + bsv);
        pk.y = f2bf(acc[m][q * 4 + 1] + bsv);
        pk.z = f2bf(acc[m][q * 4 + 2] + bsv);
        pk.w = f2bf(acc[m][q * 4 + 3] + bsv);
        *(ushort4*)(vt + ((size_t)bidx * 512 + e) * 1024 + cpos) = pk;  // vt[b][d][c]
      }
    }
  }
}

// ---------------- K3: scores, 64x128 tiles, exact triangular grid (72 per batch) ----------
__device__ const unsigned char T64_IT[72] = {
  0,1,2,2,3,3,4,4,4,5,5,5,6,6,6,6,7,7,7,7,
  8,8,8,8,8,9,9,9,9,9,10,10,10,10,10,10,11,11,11,11,11,11,
  12,12,12,12,12,12,12,13,13,13,13,13,13,13,
  14,14,14,14,14,14,14,14,15,15,15,15,15,15,15,15};
__device__ const unsigned char T64_JT[72] = {
  0,0,0,1,0,1,0,1,2,0,1,2,0,1,2,3,0,1,2,3,
  0,1,2,3,4,0,1,2,3,4,0,1,2,3,4,5,0,1,2,3,4,5,
  0,1,2,3,4,5,6,0,1,2,3,4,5,6,
  0,1,2,3,4,5,6,7,0,1,2,3,4,5,6,7};

__global__ __launch_bounds__(256, 3) void scores_kernel(const unsigned short* __restrict__ qr,
                                                        const unsigned short* __restrict__ kr,
                                                        unsigned short* __restrict__ S) {
  int it = T64_IT[blockIdx.x], jt = T64_JT[blockIdx.x], b = blockIdx.y;
  __shared__ __align__(16) unsigned short sA[2 * 4096];
  __shared__ __align__(16) unsigned short sB[2 * 8192];
  int t = threadIdx.x, w = t >> 6, l = t & 63;
  int cl = l & 31, hi = l >> 5;
  const unsigned short* A  = qr + ((size_t)b << 19) + (size_t)it * 64 * 512;
  const unsigned short* Bp = kr + ((size_t)b << 19) + (size_t)jt * 128 * 512;
  f32x16 acc[2] = {};
  gemm_pipe64(A, 512, Bp, 512, 8, sA, sB, t, acc);

  const float scale = 0.04419417382415922f;  // 1/sqrt(512)
  unsigned short* Sb = S + ((size_t)b << 20);
  int j = jt * 128 + w * 32 + cl;
#pragma unroll
  for (int m = 0; m < 2; ++m) {
    int iqb = it * 64 + m * 32 + 4 * hi;
#pragma unroll
    for (int r = 0; r < 16; ++r)
      Sb[(size_t)(iqb + (r & 3) + 8 * (r >> 2)) * 1024 + j] = f2bf(acc[m][r] * scale);
  }
}

// ---------------- K4: causal row softmax (bf16 in/out), one wave/row (unchanged) ----------
__global__ __launch_bounds__(256) void softmax_kernel(const unsigned short* __restrict__ S,
                                                      unsigned short* __restrict__ P) {
  int w = threadIdx.x >> 6, l = threadIdx.x & 63;
  int i = blockIdx.x * 4 + w;              // row 0..1023
  int b = blockIdx.y;
  const unsigned short* row = S + ((size_t)b << 20) + (size_t)i * 1024;
  unsigned short* prow = P + ((size_t)b << 20) + (size_t)i * 1024;
  int len  = i + 1;
  int jmax = ((i >> 7) + 1) << 7;          // zero-fill to end of 128-block
  float v[16];
  float mx = -3.4e38f;
#pragma unroll
  for (int c = 0; c < 2; ++c) {
    short8 raw = *(const short8*)(row + c * 512 + l * 8);
#pragma unroll
    for (int jj = 0; jj < 8; ++jj) {
      int j = c * 512 + l * 8 + jj;
      float f = bf2f((unsigned short)raw[jj]);
      v[c * 8 + jj] = (j < len) ? f : -3.4e38f;
      mx = fmaxf(mx, v[c * 8 + jj]);
    }
  }
#pragma unroll
  for (int o = 32; o > 0; o >>= 1) mx = fmaxf(mx, __shfl_xor(mx, o));
  float sm = 0.0f;
#pragma unroll
  for (int p = 0; p < 16; ++p) {
    int j = (p >> 3) * 512 + l * 8 + (p & 7);
    v[p] = (j < len) ? __expf(v[p] - mx) : 0.0f;
    sm += v[p];
  }
#pragma unroll
  for (int o = 32; o > 0; o >>= 1) sm += __shfl_xor(sm, o);
  float inv = 1.0f / sm;
#pragma unroll
  for (int c = 0; c < 2; ++c) {
    int jbase = c * 512 + l * 8;
    if (jbase < jmax) {
      short8 outv;
#pragma unroll
      for (int jj = 0; jj < 8; ++jj) outv[jj] = (short)f2bf(v[c * 8 + jj] * inv);
      *(short8*)(prow + jbase) = outv;
    }
  }
}

// ---------------- K5: out = P @ V, 64x128 out-tiles ----------------
__global__ __launch_bounds__(256, 3) void pv_kernel(const unsigned short* __restrict__ P,
                                                    const unsigned short* __restrict__ vt,
                                                    float* __restrict__ out) {
  int it = blockIdx.x, nt2 = blockIdx.y, b = blockIdx.z;
  __shared__ __align__(16) unsigned short sA[2 * 4096];
  __shared__ __align__(16) unsigned short sB[2 * 8192];
  int t = threadIdx.x, w = t >> 6, l = t & 63;
  int cl = l & 31, hi = l >> 5;
  const unsigned short* A  = P  + ((size_t)b << 20) + (size_t)it * 64 * 1024;
  const unsigned short* Bp = vt + ((size_t)b << 19) + (size_t)nt2 * 128 * 1024;
  int nt = ((it >> 1) + 1) * 2;   // causal: kv < ((it>>1)+1)*128, K-tiles of 64
  f32x16 acc[2] = {};
  gemm_pipe64(A, 1024, Bp, 1024, nt, sA, sB, t, acc);

  float* ob = out + ((size_t)b << 19);
  int d = nt2 * 128 + w * 32 + cl;
#pragma unroll
  for (int m = 0; m < 2; ++m) {
    int iqb = it * 64 + m * 32 + 4 * hi;
#pragma unroll
    for (int r = 0; r < 16; ++r)
      ob[(size_t)(iqb + (r & 3) + 8 * (r >> 2)) * 512 + d] = acc[m][r];
  }
}

// ---------------- launch ----------------
extern "C" void kernel_launch(void* const* d_in, const int* in_sizes, int n_in,
                              void* d_out, int out_size, void* d_ws, size_t ws_size,
                              hipStream_t stream) {
  const float* x  = (const float*)d_in[0];
  const float* wq = (const float*)d_in[1];
  const float* bq = (const float*)d_in[2];
  const float* wk = (const float*)d_in[3];
  const float* bk = (const float*)d_in[4];
  const float* wv = (const float*)d_in[5];
  const float* bv = (const float*)d_in[6];
  float* out = (float*)d_out;

  char* ws = (char*)d_ws;
  float2*         tab  = (float2*)(ws);                          //  2 MB
  unsigned short* xb   = (unsigned short*)(ws + (2ull  << 20));  //  8 MB
  unsigned short* wb   = (unsigned short*)(ws + (10ull << 20));  //  1.5 MB
  unsigned short* qrot = (unsigned short*)(ws + (12ull << 20));  //  8 MB
  unsigned short* krot = (unsigned short*)(ws + (20ull << 20));  //  8 MB
  unsigned short* vt   = (unsigned short*)(ws + (28ull << 20));  //  8 MB
  unsigned short* S    = (unsigned short*)(ws + (36ull << 20));  // 16 MB
  unsigned short* P    = (unsigned short*)(ws + (52ull << 20));  // 16 MB -> total 68 MB

  prep_all<<<dim3(CAST_BLOCKS + CTXN), dim3(256), 0, stream>>>(x, wq, wk, wv, xb, wb, tab);
  qkv_kernel<<<dim3(64, 12), dim3(512), 0, stream>>>(xb, wb, bq, bk, bv, tab, qrot, krot, vt);
  scores_kernel<<<dim3(72, BATCH), dim3(256), 0, stream>>>(qrot, krot, S);
  softmax_kernel<<<dim3(256, BATCH), dim3(256), 0, stream>>>(S, P);
  pv_kernel<<<dim3(16, 4, BATCH), dim3(256), 0, stream>>>(P, vt, out);
}